// Round 2
// baseline (105.782 us; speedup 1.0000x reference)
//
#include <hip/hip_runtime.h>
#include <math.h>

#define NCC 80
#define TOPKK 13
#define BB 16
#define NAA 8400
#define NMX 64
#define NCH 16       // chunks per gt-row in stage A
#define CHSZ 525     // NAA / NCH
#define NCAND (NCH * TOPKK)   // 208 candidates per row into stage B
#define EPSF 1e-9f
#define IOUEPS 1e-7f
#define INV_PI2 0.4052847345693511f

__device__ __forceinline__ float ciou2(float gx1, float gy1, float gx2, float gy2,
                                       float gw, float gh, float gat,
                                       float px1, float py1, float px2, float py2,
                                       float pat)
{
    float w2 = px2 - px1, h2 = py2 - py1;
    float iw = fmaxf(fminf(gx2, px2) - fmaxf(gx1, px1), 0.f);
    float ih = fmaxf(fminf(gy2, py2) - fmaxf(gy1, py1), 0.f);
    float inter = iw * ih;
    float uni = gw * gh + w2 * h2 - inter + IOUEPS;
    float iou = inter / uni;
    float cw = fmaxf(gx2, px2) - fminf(gx1, px1);
    float ch = fmaxf(gy2, py2) - fminf(gy1, py1);
    float c2 = cw * cw + ch * ch + IOUEPS;
    float dx = px1 + px2 - gx1 - gx2;
    float dy = py1 + py2 - gy1 - gy2;
    float rho2 = (dx * dx + dy * dy) * 0.25f;
    float da = pat - gat;
    float v = INV_PI2 * da * da;
    float alpha = v / (v - iou + (1.f + IOUEPS));
    return iou - (rho2 / c2 + v * alpha);
}

// K0: hoist atan(w/h) for all pred boxes and gt boxes.
__global__ __launch_bounds__(256) void k0_atan(
    const float* __restrict__ pd_bboxes, const float* __restrict__ gt_bboxes,
    float* __restrict__ patan, float* __restrict__ gatan)
{
    int id = blockIdx.x * 256 + threadIdx.x;
    if (id < BB * NAA) {
        float4 p = reinterpret_cast<const float4*>(pd_bboxes)[id];
        patan[id] = atanf((p.z - p.x) / (p.w - p.y));
    }
    if (id < BB * NMX) {
        float4 g = reinterpret_cast<const float4*>(gt_bboxes)[id];
        gatan[id] = atanf((g.z - g.x) / (g.w - g.y));
    }
}

// K1a: one wave per (row, chunk). Per-lane lexicographic top-13 over ~9 anchors,
// then 13 rounds of shfl-butterfly argmax (value desc, index asc). No barriers
// beyond single-wave LDS ordering.
__global__ __launch_bounds__(64) void k1a_partial(
    const float* __restrict__ pd_scores,
    const float* __restrict__ pd_bboxes,
    const float* __restrict__ anc,
    const int*   __restrict__ gt_labels,
    const float* __restrict__ gt_bboxes,
    const float* __restrict__ mask_gt,
    const float* __restrict__ patan,
    const float* __restrict__ gatan,
    float* __restrict__ candV, int* __restrict__ candI)
{
    const int chunk = blockIdx.x;
    const int row = blockIdx.y;
    if (mask_gt[row] <= 0.f) return;
    const int b = row >> 6;
    const int lane = threadIdx.x;

    const float4 g = reinterpret_cast<const float4*>(gt_bboxes)[row];
    const float gw = g.z - g.x, gh = g.w - g.y;
    const float gat = gatan[row];
    const int gl = gt_labels[row];
    const float* sc = pd_scores + (size_t)b * NAA * NCC + gl;
    const float4* pb = reinterpret_cast<const float4*>(pd_bboxes) + (size_t)b * NAA;
    const float* pat = patan + (size_t)b * NAA;
    const float2* ap2 = reinterpret_cast<const float2*>(anc);

    float lv[TOPKK]; int li[TOPKK];
#pragma unroll
    for (int k = 0; k < TOPKK; k++) { lv[k] = -1.f; li[k] = 0x7fffffff; }

    const int a0 = chunk * CHSZ;
    for (int a = a0 + lane; a < a0 + CHSZ; a += 64) {
        float2 ap = ap2[a];
        float din = fminf(fminf(ap.x - g.x, ap.y - g.y), fminf(g.z - ap.x, g.w - ap.y));
        float al = 0.f;
        if (din > EPSF) {
            float4 p = pb[a];
            float c = ciou2(g.x, g.y, g.z, g.w, gw, gh, gat, p.x, p.y, p.z, p.w, pat[a]);
            float o = fmaxf(c, 0.f);
            float o2 = o * o;
            al = sc[(size_t)a * NCC] * (o2 * o2 * o2);
        }
        // lexicographic sorted insert: key = (value desc, index asc)
        if (al > lv[TOPKK - 1] || (al == lv[TOPKK - 1] && a < li[TOPKK - 1])) {
            lv[TOPKK - 1] = al; li[TOPKK - 1] = a;
#pragma unroll
            for (int k = TOPKK - 1; k > 0; --k) {
                if (lv[k] > lv[k - 1] || (lv[k] == lv[k - 1] && li[k] < li[k - 1])) {
                    float tv = lv[k]; lv[k] = lv[k - 1]; lv[k - 1] = tv;
                    int ti = li[k]; li[k] = li[k - 1]; li[k - 1] = ti;
                } else break;
            }
        }
    }

    // per-lane lists to LDS so the head pointer can be runtime-indexed
    __shared__ float Lv[64 * TOPKK];
    __shared__ int   Li[64 * TOPKK];
#pragma unroll
    for (int k = 0; k < TOPKK; k++) { Lv[lane * TOPKK + k] = lv[k]; Li[lane * TOPKK + k] = li[k]; }
    __syncthreads();  // single wave: cheap

    int p = 0;
    float myv = -1.f; int myi = 0x7fffffff;
    for (int r = 0; r < TOPKK; ++r) {
        float hv = (p < TOPKK) ? Lv[lane * TOPKK + p] : -2.f;
        int   hi = (p < TOPKK) ? Li[lane * TOPKK + p] : 0x7fffffff;
        float wv = hv; int wi = hi;
#pragma unroll
        for (int s = 1; s < 64; s <<= 1) {
            float ov = __shfl_xor(wv, s, 64);
            int   oi = __shfl_xor(wi, s, 64);
            if (ov > wv || (ov == wv && oi < wi)) { wv = ov; wi = oi; }
        }
        if (lane == r) { myv = wv; myi = wi; }
        if (p < TOPKK && hi == wi) ++p;
    }
    if (lane < TOPKK) {
        candV[(size_t)row * NCAND + chunk * TOPKK + lane] = myv;
        candI[(size_t)row * NCAND + chunk * TOPKK + lane] = myi;
    }
}

// K1b: one wave per row. Merge 208 candidates -> global top-13, scatter cnt/jsum.
__global__ __launch_bounds__(64) void k1b_merge(
    const float* __restrict__ candV, const int* __restrict__ candI,
    const float* __restrict__ anc,
    const float* __restrict__ gt_bboxes,
    const float* __restrict__ mask_gt,
    int* __restrict__ cnt, int* __restrict__ jsum)
{
    const int row = blockIdx.x;
    if (mask_gt[row] <= 0.f) return;
    const int b = row >> 6, j = row & 63;
    const int lane = threadIdx.x;

    float v0 = -1e30f, v1 = -1e30f, v2 = -1e30f, v3 = -1e30f;
    int i0 = 0x7fffffff, i1 = 0x7fffffff, i2 = 0x7fffffff, i3 = 0x7fffffff;
    const float* cv = candV + (size_t)row * NCAND;
    const int*   ci = candI + (size_t)row * NCAND;
    { int e = lane;        v0 = cv[e]; i0 = ci[e]; }
    { int e = lane + 64;   v1 = cv[e]; i1 = ci[e]; }
    { int e = lane + 128;  v2 = cv[e]; i2 = ci[e]; }
    if (lane + 192 < NCAND) { int e = lane + 192; v3 = cv[e]; i3 = ci[e]; }

    int myi = 0x7fffffff;
    for (int r = 0; r < TOPKK; ++r) {
        float bv = v0; int bi = i0;
        if (v1 > bv || (v1 == bv && i1 < bi)) { bv = v1; bi = i1; }
        if (v2 > bv || (v2 == bv && i2 < bi)) { bv = v2; bi = i2; }
        if (v3 > bv || (v3 == bv && i3 < bi)) { bv = v3; bi = i3; }
        float wv = bv; int wi = bi;
#pragma unroll
        for (int s = 1; s < 64; s <<= 1) {
            float ov = __shfl_xor(wv, s, 64);
            int   oi = __shfl_xor(wi, s, 64);
            if (ov > wv || (ov == wv && oi < wi)) { wv = ov; wi = oi; }
        }
        if (lane == r) myi = wi;
        if (i0 == wi) v0 = -1e30f;
        if (i1 == wi) v1 = -1e30f;
        if (i2 == wi) v2 = -1e30f;
        if (i3 == wi) v3 = -1e30f;
    }

    if (lane < TOPKK) {
        int a = myi;
        float4 g = reinterpret_cast<const float4*>(gt_bboxes)[row];
        float2 ap = reinterpret_cast<const float2*>(anc)[a];
        float din = fminf(fminf(ap.x - g.x, ap.y - g.y), fminf(g.z - ap.x, g.w - ap.y));
        if (din > EPSF) {
            atomicAdd(&cnt[(size_t)b * NAA + a], 1);
            atomicAdd(&jsum[(size_t)b * NAA + a], j);
        }
    }
}

// K2: per-anchor multi-gt resolution + per-row pos_align/pos_ovl maxima.
__global__ __launch_bounds__(256) void k2_resolve(
    const float* __restrict__ pd_scores,
    const float* __restrict__ pd_bboxes,
    const float* __restrict__ anc,
    const int*   __restrict__ gt_labels,
    const float* __restrict__ gt_bboxes,
    const float* __restrict__ mask_gt,
    const float* __restrict__ patan,
    const float* __restrict__ gatan,
    const int* __restrict__ cnt, const int* __restrict__ jsum,
    int* __restrict__ tgt, int* __restrict__ fgm, float* __restrict__ alv,
    unsigned int* __restrict__ pos_al, unsigned int* __restrict__ pos_ov)
{
    const size_t id = (size_t)blockIdx.x * 256 + threadIdx.x;
    if (id >= (size_t)BB * NAA) return;
    const int b = (int)(id / NAA);
    const int a = (int)(id % NAA);
    const int fg = cnt[id];
    float2 ap = reinterpret_cast<const float2*>(anc)[a];
    float4 p = reinterpret_cast<const float4*>(pd_bboxes)[id];
    float pat = patan[id];
    int tj = 0, f = 0;
    if (fg == 1) { tj = jsum[id]; f = 1; }
    else if (fg > 1) {
        f = 1;
        float bv = -1.f; int bj = 0;
        for (int j = 0; j < NMX; ++j) {
            float4 g = reinterpret_cast<const float4*>(gt_bboxes)[b * NMX + j];
            float din = fminf(fminf(ap.x - g.x, ap.y - g.y), fminf(g.z - ap.x, g.w - ap.y));
            float ov = 0.f;
            if (din > EPSF && mask_gt[b * NMX + j] > 0.f) {
                float gw = g.z - g.x, gh = g.w - g.y;
                float c = ciou2(g.x, g.y, g.z, g.w, gw, gh, gatan[b * NMX + j],
                                p.x, p.y, p.z, p.w, pat);
                ov = fmaxf(c, 0.f);
            }
            if (ov > bv) { bv = ov; bj = j; }  // strict > == first-argmax
        }
        tj = bj;
    }
    float al = 0.f;
    if (f) {
        float4 g = reinterpret_cast<const float4*>(gt_bboxes)[b * NMX + tj];
        float din = fminf(fminf(ap.x - g.x, ap.y - g.y), fminf(g.z - ap.x, g.w - ap.y));
        if (din > EPSF && mask_gt[b * NMX + tj] > 0.f) {
            float gw = g.z - g.x, gh = g.w - g.y;
            float c = ciou2(g.x, g.y, g.z, g.w, gw, gh, gatan[b * NMX + tj],
                            p.x, p.y, p.z, p.w, pat);
            float ov = fmaxf(c, 0.f);
            int gl = gt_labels[b * NMX + tj];
            float s = pd_scores[(size_t)(b * NAA + a) * NCC + gl];
            float o2 = ov * ov;
            al = s * (o2 * o2 * o2);
            atomicMax(&pos_ov[b * NMX + tj], __float_as_uint(ov));
        } else {
            atomicMax(&pos_ov[b * NMX + tj], 0u);
        }
        atomicMax(&pos_al[b * NMX + tj], __float_as_uint(al));
    }
    tgt[id] = tj; fgm[id] = f; alv[id] = al;
}

// K3: final outputs.
__global__ __launch_bounds__(256) void k3_out(
    const int* __restrict__ gt_labels,
    const float* __restrict__ gt_bboxes,
    const int* __restrict__ tgt, const int* __restrict__ fgm,
    const float* __restrict__ alv,
    const unsigned int* __restrict__ pos_al, const unsigned int* __restrict__ pos_ov,
    float* __restrict__ o_lab, float* __restrict__ o_box, float* __restrict__ o_sc,
    float* __restrict__ o_fg, float* __restrict__ o_ti)
{
    const size_t id = (size_t)blockIdx.x * 256 + threadIdx.x;
    if (id >= (size_t)BB * NAA) return;
    const int b = (int)(id / NAA);
    const int tj = tgt[id];
    const int f = fgm[id];
    int lab = gt_labels[b * NMX + tj]; lab = lab < 0 ? 0 : lab;
    float4 gb = reinterpret_cast<const float4*>(gt_bboxes)[b * NMX + tj];
    o_lab[id] = (float)lab;
    reinterpret_cast<float4*>(o_box)[id] = gb;
    o_fg[id] = f ? 1.f : 0.f;
    o_ti[id] = (float)tj;
    if (f) {
        float pa = __uint_as_float(pos_al[b * NMX + tj]);
        float po = __uint_as_float(pos_ov[b * NMX + tj]);
        o_sc[id * NCC + lab] = (alv[id] * po) / (pa + EPSF);
    }
}

extern "C" void kernel_launch(void* const* d_in, const int* in_sizes, int n_in,
                              void* d_out, int out_size, void* d_ws, size_t ws_size,
                              hipStream_t stream)
{
    const float* pd_scores = (const float*)d_in[0];
    const float* pd_bboxes = (const float*)d_in[1];
    const float* anc       = (const float*)d_in[2];
    // d_in[3] rfields: unused by the reference
    const int*   gt_labels = (const int*)d_in[4];
    const float* gt_bboxes = (const float*)d_in[5];
    const float* mask_gt   = (const float*)d_in[6];

    const size_t nba = (size_t)BB * NAA;          // 134400
    const size_t nrow = (size_t)BB * NMX;         // 1024
    int* cnt   = (int*)d_ws;
    int* jsum  = cnt + nba;
    int* tgt   = jsum + nba;
    int* fgm   = tgt + nba;
    float* alv = (float*)(fgm + nba);
    unsigned int* pos_al = (unsigned int*)(alv + nba);
    unsigned int* pos_ov = pos_al + nrow;
    float* patan = (float*)(pos_ov + nrow);
    float* gatan = patan + nba;
    float* candV = gatan + nrow;
    int*   candI = (int*)(candV + nrow * NCAND);

    float* out = (float*)d_out;
    float* o_lab = out;                 // (B,NA)
    float* o_box = out + nba;           // (B,NA,4)
    float* o_sc  = out + nba * 5;       // (B,NA,NC)
    float* o_fg  = out + nba * 85;      // (B,NA)
    float* o_ti  = out + nba * 86;      // (B,NA)

    // only the sparse-scattered score region needs pre-zeroing
    hipMemsetAsync(o_sc, 0, nba * NCC * sizeof(float), stream);
    hipMemsetAsync(cnt, 0, nba * 2 * sizeof(int), stream);
    hipMemsetAsync(pos_al, 0, nrow * 2 * sizeof(unsigned int), stream);

    k0_atan<<<(int)((nba + 255) / 256), 256, 0, stream>>>(pd_bboxes, gt_bboxes, patan, gatan);
    k1a_partial<<<dim3(NCH, (unsigned)nrow), 64, 0, stream>>>(
        pd_scores, pd_bboxes, anc, gt_labels, gt_bboxes, mask_gt,
        patan, gatan, candV, candI);
    k1b_merge<<<(int)nrow, 64, 0, stream>>>(candV, candI, anc, gt_bboxes, mask_gt, cnt, jsum);
    const int nblk = (int)((nba + 255) / 256);
    k2_resolve<<<nblk, 256, 0, stream>>>(pd_scores, pd_bboxes, anc, gt_labels,
                                         gt_bboxes, mask_gt, patan, gatan,
                                         cnt, jsum, tgt, fgm, alv, pos_al, pos_ov);
    k3_out<<<nblk, 256, 0, stream>>>(gt_labels, gt_bboxes, tgt, fgm, alv,
                                     pos_al, pos_ov, o_lab, o_box, o_sc, o_fg, o_ti);
}

// Round 3
// 68.020 us; speedup vs baseline: 1.5552x; 1.5552x over previous
//
#include <hip/hip_runtime.h>
#include <math.h>

#define NCC 80
#define TOPKK 13
#define BB 16
#define NAA 8400
#define NMX 64
#define LCAP 2048      // compacted candidate list capacity (worst realistic ~650)
#define PDEPTH 8       // per-thread sorted list depth = ceil(LCAP/256)
#define PSTR 9         // padded LDS stride (conflict-free, free sentinel slot)
#define EPSF 1e-9f
#define IOUEPS 1e-7f
#define INV_PI2 0.4052847345693511f

__device__ __forceinline__ float ciou2(float gx1, float gy1, float gx2, float gy2,
                                       float gw, float gh, float gat,
                                       float px1, float py1, float px2, float py2,
                                       float pat)
{
    float w2 = px2 - px1, h2 = py2 - py1;
    float iw = fmaxf(fminf(gx2, px2) - fmaxf(gx1, px1), 0.f);
    float ih = fmaxf(fminf(gy2, py2) - fmaxf(gy1, py1), 0.f);
    float inter = iw * ih;
    float uni = gw * gh + w2 * h2 - inter + IOUEPS;
    float iou = inter / uni;
    float cw = fmaxf(gx2, px2) - fminf(gx1, px1);
    float ch = fmaxf(gy2, py2) - fminf(gy1, py1);
    float c2 = cw * cw + ch * ch + IOUEPS;
    float dx = px1 + px2 - gx1 - gx2;
    float dy = py1 + py2 - gy1 - gy2;
    float rho2 = (dx * dx + dy * dy) * 0.25f;
    float da = pat - gat;
    float v = INV_PI2 * da * da;
    float alpha = v / (v - iou + (1.f + IOUEPS));
    return iou - (rho2 / c2 + v * alpha);
}

// K1: one 256-thread block per (b,j) row.
// Pass 1: ballot-compact S = {in-gt anchors} U {0..12} into LDS (exact top-13
//         of the full row is provably a subset of S).
// Pass 2: compute align_metric only on S; per-thread sorted list (depth 8 holds
//         ALL of a thread's candidates); 13-round tournament merge with exact
//         (value desc, index asc) lax.top_k ordering; scatter cnt/jsum.
__global__ __launch_bounds__(256) void k1_topk(
    const float* __restrict__ pd_scores,
    const float* __restrict__ pd_bboxes,
    const float* __restrict__ anc,
    const int*   __restrict__ gt_labels,
    const float* __restrict__ gt_bboxes,
    const float* __restrict__ mask_gt,
    int* __restrict__ cnt, int* __restrict__ jsum)
{
    const int row = blockIdx.x;
    if (mask_gt[row] <= 0.f) return;
    const int b = row >> 6, j = row & 63;
    const int tid = threadIdx.x;
    const int lane = tid & 63, wid = tid >> 6;

    const float4 g = reinterpret_cast<const float4*>(gt_bboxes)[row];
    const float gw = g.z - g.x, gh = g.w - g.y;
    const float gat = atanf(gw / gh);
    const int gl = gt_labels[row];
    const float* sc = pd_scores + (size_t)b * NAA * NCC + gl;
    const float4* pb = reinterpret_cast<const float4*>(pd_bboxes) + (size_t)b * NAA;
    const float2* ap2 = reinterpret_cast<const float2*>(anc);

    __shared__ int   list[LCAP];
    __shared__ int   nlist;
    __shared__ float wv4[4];
    __shared__ int   wi4[4];
    __shared__ int   win[TOPKK];
    __shared__ float Lv[256 * PSTR];
    __shared__ int   Li[256 * PSTR];

    if (tid == 0) nlist = 0;
    __syncthreads();

    // ---- pass 1: compact candidate set ----
    for (int a = tid; a < NAA; a += 256) {
        float2 ap = ap2[a];
        float din = fminf(fminf(ap.x - g.x, ap.y - g.y), fminf(g.z - ap.x, g.w - ap.y));
        bool take = (din > EPSF) || (a < TOPKK);
        unsigned long long m = __ballot(take);
        if (m) {
            int base = 0;
            int wcnt = __popcll(m);
            if (lane == 0) base = atomicAdd(&nlist, wcnt);
            base = __shfl(base, 0, 64);
            if (take) {
                int pos = base + __popcll(m & ((1ull << lane) - 1ull));
                if (pos < LCAP) list[pos] = a;
            }
        }
    }
    __syncthreads();
    int nc = nlist; if (nc > LCAP) nc = LCAP;

    // ---- pass 2: align_metric on candidates, per-thread sorted list ----
    float lv[PDEPTH]; int li[PDEPTH];
#pragma unroll
    for (int k = 0; k < PDEPTH; k++) { lv[k] = -1.f; li[k] = 0x7fffffff; }

    for (int t = tid; t < nc; t += 256) {
        int a = list[t];
        float al = 0.f;
        float2 ap = ap2[a];
        float din = fminf(fminf(ap.x - g.x, ap.y - g.y), fminf(g.z - ap.x, g.w - ap.y));
        if (din > EPSF) {
            float4 p = pb[a];
            float pat = atanf((p.z - p.x) / (p.w - p.y));
            float c = ciou2(g.x, g.y, g.z, g.w, gw, gh, gat, p.x, p.y, p.z, p.w, pat);
            float o = fmaxf(c, 0.f);
            float o2 = o * o;
            al = sc[(size_t)a * NCC] * (o2 * o2 * o2);
        }
        if (al > lv[PDEPTH - 1] || (al == lv[PDEPTH - 1] && a < li[PDEPTH - 1])) {
            lv[PDEPTH - 1] = al; li[PDEPTH - 1] = a;
#pragma unroll
            for (int k = PDEPTH - 1; k > 0; --k) {
                if (lv[k] > lv[k - 1] || (lv[k] == lv[k - 1] && li[k] < li[k - 1])) {
                    float tv = lv[k]; lv[k] = lv[k - 1]; lv[k - 1] = tv;
                    int ti = li[k]; li[k] = li[k - 1]; li[k - 1] = ti;
                } else break;
            }
        }
    }
#pragma unroll
    for (int k = 0; k < PDEPTH; k++) { Lv[tid * PSTR + k] = lv[k]; Li[tid * PSTR + k] = li[k]; }
    Lv[tid * PSTR + PDEPTH] = -1.f;            // sentinel for exhausted head
    Li[tid * PSTR + PDEPTH] = 0x7fffffff;

    // ---- 13-round tournament merge (exact lexicographic order) ----
    int p = 0;
    for (int r = 0; r < TOPKK; ++r) {
        float hv = Lv[tid * PSTR + p];
        int   hi = Li[tid * PSTR + p];
        float wv = hv; int wi = hi;
#pragma unroll
        for (int s = 1; s < 64; s <<= 1) {
            float ov = __shfl_xor(wv, s, 64);
            int   oi = __shfl_xor(wi, s, 64);
            if (ov > wv || (ov == wv && oi < wi)) { wv = ov; wi = oi; }
        }
        if (lane == 0) { wv4[wid] = wv; wi4[wid] = wi; }
        __syncthreads();
        float gv = wv4[0]; int gi = wi4[0];
#pragma unroll
        for (int w = 1; w < 4; ++w) {
            float ov = wv4[w]; int oi = wi4[w];
            if (ov > gv || (ov == gv && oi < gi)) { gv = ov; gi = oi; }
        }
        if (hi == gi) ++p;                      // my head consumed
        if (tid == 0) win[r] = gi;
        __syncthreads();
    }

    // ---- scatter: winners passing mask_in_gts ----
    if (tid < TOPKK) {
        int a = win[tid];
        float2 ap = ap2[a];
        float din = fminf(fminf(ap.x - g.x, ap.y - g.y), fminf(g.z - ap.x, g.w - ap.y));
        if (din > EPSF) {
            atomicAdd(&cnt[(size_t)b * NAA + a], 1);
            atomicAdd(&jsum[(size_t)b * NAA + a], j);
        }
    }
}

// K2: per-anchor multi-gt resolution + per-row pos_align/pos_ovl maxima.
__global__ __launch_bounds__(256) void k2_resolve(
    const float* __restrict__ pd_scores,
    const float* __restrict__ pd_bboxes,
    const float* __restrict__ anc,
    const int*   __restrict__ gt_labels,
    const float* __restrict__ gt_bboxes,
    const float* __restrict__ mask_gt,
    const int* __restrict__ cnt, const int* __restrict__ jsum,
    int* __restrict__ tgt, int* __restrict__ fgm, float* __restrict__ alv,
    unsigned int* __restrict__ pos_al, unsigned int* __restrict__ pos_ov)
{
    const int id = blockIdx.x * 256 + threadIdx.x;   // grid covers exactly B*NA
    const int b = id / NAA;
    const int a = id - b * NAA;
    const int fg = cnt[id];
    int tj = 0, f = 0;
    float al = 0.f;
    if (fg > 0) {
        f = 1;
        float2 ap = reinterpret_cast<const float2*>(anc)[a];
        float4 p = reinterpret_cast<const float4*>(pd_bboxes)[id];
        float pat = atanf((p.z - p.x) / (p.w - p.y));
        if (fg == 1) {
            tj = jsum[id];
        } else {
            float bv = -1.f; int bj = 0;
            for (int jj = 0; jj < NMX; ++jj) {
                float4 g = reinterpret_cast<const float4*>(gt_bboxes)[b * NMX + jj];
                float din = fminf(fminf(ap.x - g.x, ap.y - g.y), fminf(g.z - ap.x, g.w - ap.y));
                float ov = 0.f;
                if (din > EPSF && mask_gt[b * NMX + jj] > 0.f) {
                    float gw = g.z - g.x, gh = g.w - g.y;
                    float c = ciou2(g.x, g.y, g.z, g.w, gw, gh, atanf(gw / gh),
                                    p.x, p.y, p.z, p.w, pat);
                    ov = fmaxf(c, 0.f);
                }
                if (ov > bv) { bv = ov; bj = jj; }   // strict > == first-argmax
            }
            tj = bj;
        }
        float4 g = reinterpret_cast<const float4*>(gt_bboxes)[b * NMX + tj];
        float din = fminf(fminf(ap.x - g.x, ap.y - g.y), fminf(g.z - ap.x, g.w - ap.y));
        if (din > EPSF && mask_gt[b * NMX + tj] > 0.f) {
            float gw = g.z - g.x, gh = g.w - g.y;
            float c = ciou2(g.x, g.y, g.z, g.w, gw, gh, atanf(gw / gh),
                            p.x, p.y, p.z, p.w, pat);
            float ov = fmaxf(c, 0.f);
            int gl = gt_labels[b * NMX + tj];
            float s = pd_scores[(size_t)id * NCC + gl];
            float o2 = ov * ov;
            al = s * (o2 * o2 * o2);
            atomicMax(&pos_ov[b * NMX + tj], __float_as_uint(ov));
        }
        atomicMax(&pos_al[b * NMX + tj], __float_as_uint(al));
    }
    tgt[id] = tj; fgm[id] = f; alv[id] = al;
}

// K3: all outputs, fully written (no memset pass). Score region written with
// coalesced float4 stores via LDS-staged (label, val) per anchor.
__global__ __launch_bounds__(256) void k3_out(
    const int* __restrict__ gt_labels,
    const float* __restrict__ gt_bboxes,
    const int* __restrict__ tgt, const int* __restrict__ fgm,
    const float* __restrict__ alv,
    const unsigned int* __restrict__ pos_al, const unsigned int* __restrict__ pos_ov,
    float* __restrict__ o_lab, float* __restrict__ o_box, float* __restrict__ o_sc,
    float* __restrict__ o_fg, float* __restrict__ o_ti)
{
    const int id0 = blockIdx.x * 256;
    const int tid = threadIdx.x;
    const int id = id0 + tid;
    const int b = id / NAA;
    const int tj = tgt[id];
    const int f = fgm[id];
    int lab = gt_labels[b * NMX + tj]; lab = lab < 0 ? 0 : lab;
    float4 gb = reinterpret_cast<const float4*>(gt_bboxes)[b * NMX + tj];
    o_lab[id] = (float)lab;
    reinterpret_cast<float4*>(o_box)[id] = gb;
    o_fg[id] = f ? 1.f : 0.f;
    o_ti[id] = (float)tj;
    float val = 0.f;
    if (f) {
        float pa = __uint_as_float(pos_al[b * NMX + tj]);
        float po = __uint_as_float(pos_ov[b * NMX + tj]);
        val = (alv[id] * po) / (pa + EPSF);
    }
    __shared__ int   s_lab[256];
    __shared__ float s_val[256];
    s_lab[tid] = lab;
    s_val[tid] = val;
    __syncthreads();
    float4* dst = reinterpret_cast<float4*>(o_sc + (size_t)id0 * NCC);
    const int NV = 256 * NCC / 4;   // 5120 float4s per block
#pragma unroll 4
    for (int i = tid; i < NV; i += 256) {
        int a  = i / (NCC / 4);
        int c0 = (i - a * (NCC / 4)) * 4;
        int la = s_lab[a];
        float v = s_val[a];
        float4 w;
        w.x = (la == c0 + 0) ? v : 0.f;
        w.y = (la == c0 + 1) ? v : 0.f;
        w.z = (la == c0 + 2) ? v : 0.f;
        w.w = (la == c0 + 3) ? v : 0.f;
        dst[i] = w;
    }
}

extern "C" void kernel_launch(void* const* d_in, const int* in_sizes, int n_in,
                              void* d_out, int out_size, void* d_ws, size_t ws_size,
                              hipStream_t stream)
{
    const float* pd_scores = (const float*)d_in[0];
    const float* pd_bboxes = (const float*)d_in[1];
    const float* anc       = (const float*)d_in[2];
    // d_in[3] rfields: unused by the reference
    const int*   gt_labels = (const int*)d_in[4];
    const float* gt_bboxes = (const float*)d_in[5];
    const float* mask_gt   = (const float*)d_in[6];

    const size_t nba  = (size_t)BB * NAA;   // 134400
    const size_t nrow = (size_t)BB * NMX;   // 1024
    int* cnt   = (int*)d_ws;
    int* jsum  = cnt + nba;
    int* tgt   = jsum + nba;
    int* fgm   = tgt + nba;
    float* alv = (float*)(fgm + nba);
    unsigned int* pos_al = (unsigned int*)(alv + nba);
    unsigned int* pos_ov = pos_al + nrow;

    float* out = (float*)d_out;
    float* o_lab = out;                 // (B,NA)
    float* o_box = out + nba;           // (B,NA,4)
    float* o_sc  = out + nba * 5;       // (B,NA,NC)
    float* o_fg  = out + nba * 85;      // (B,NA)
    float* o_ti  = out + nba * 86;      // (B,NA)

    hipMemsetAsync(cnt, 0, nba * 2 * sizeof(int), stream);
    hipMemsetAsync(pos_al, 0, nrow * 2 * sizeof(unsigned int), stream);

    k1_topk<<<(int)nrow, 256, 0, stream>>>(pd_scores, pd_bboxes, anc, gt_labels,
                                           gt_bboxes, mask_gt, cnt, jsum);
    const int nblk = (int)(nba / 256);   // 525, exact
    k2_resolve<<<nblk, 256, 0, stream>>>(pd_scores, pd_bboxes, anc, gt_labels,
                                         gt_bboxes, mask_gt, cnt, jsum,
                                         tgt, fgm, alv, pos_al, pos_ov);
    k3_out<<<nblk, 256, 0, stream>>>(gt_labels, gt_bboxes, tgt, fgm, alv,
                                     pos_al, pos_ov, o_lab, o_box, o_sc, o_fg, o_ti);
}

// Round 4
// 64.791 us; speedup vs baseline: 1.6327x; 1.0498x over previous
//
#include <hip/hip_runtime.h>
#include <math.h>

#define NCC 80
#define TOPKK 13
#define BB 16
#define NAA 8400
#define NMX 64
#define LCAP 2048      // compacted candidate list capacity (worst realistic ~650)
#define PDEPTH 8       // per-thread sorted list depth = ceil(LCAP/256)
#define PSTR 9         // padded LDS stride (conflict-free, free sentinel slot)
#define EPSF 1e-9f
#define IOUEPS 1e-7f
#define INV_PI2 0.4052847345693511f

// zero region: cnt (B*NA) + pos_al (1024) + pos_ov (1024), contiguous ints
#define NZI (BB * NAA + 2 * BB * NMX)   // 136448 ints
#define NZI4 (NZI / 4)                  // 34112 int4s (NZI % 4 == 0)

__device__ __forceinline__ float ciou2(float gx1, float gy1, float gx2, float gy2,
                                       float gw, float gh, float gat,
                                       float px1, float py1, float px2, float py2,
                                       float pat)
{
    float w2 = px2 - px1, h2 = py2 - py1;
    float iw = fmaxf(fminf(gx2, px2) - fmaxf(gx1, px1), 0.f);
    float ih = fmaxf(fminf(gy2, py2) - fmaxf(gy1, py1), 0.f);
    float inter = iw * ih;
    float uni = gw * gh + w2 * h2 - inter + IOUEPS;
    float iou = inter / uni;
    float cw = fmaxf(gx2, px2) - fminf(gx1, px1);
    float ch = fmaxf(gy2, py2) - fminf(gy1, py1);
    float c2 = cw * cw + ch * ch + IOUEPS;
    float dx = px1 + px2 - gx1 - gx2;
    float dy = py1 + py2 - gy1 - gy2;
    float rho2 = (dx * dx + dy * dy) * 0.25f;
    float da = pat - gat;
    float v = INV_PI2 * da * da;
    float alpha = v / (v - iou + (1.f + IOUEPS));
    return iou - (rho2 / c2 + v * alpha);
}

// KZ: zero the atomic scratch (replaces latency-bound rocclr fill kernels).
__global__ __launch_bounds__(256) void kz_zero(int4* __restrict__ z)
{
    int i = blockIdx.x * 256 + threadIdx.x;
    if (i < NZI4) z[i] = make_int4(0, 0, 0, 0);
}

// K1: one 256-thread block per (b,j) row.
// Pass 1: ballot-compact S = {in-gt anchors} U {0..12} into LDS (exact top-13
//         of the full row is provably a subset of S).
// Pass 2: align_metric only on S; per-thread sorted list; 13-round tournament
//         merge with exact (value desc, index asc) lax.top_k ordering; scatter
//         packed count|jsum.
__global__ __launch_bounds__(256) void k1_topk(
    const float* __restrict__ pd_scores,
    const float* __restrict__ pd_bboxes,
    const float* __restrict__ anc,
    const int*   __restrict__ gt_labels,
    const float* __restrict__ gt_bboxes,
    const float* __restrict__ mask_gt,
    int* __restrict__ cnt)
{
    const int row = blockIdx.x;
    if (mask_gt[row] <= 0.f) return;
    const int b = row >> 6, j = row & 63;
    const int tid = threadIdx.x;
    const int lane = tid & 63, wid = tid >> 6;

    const float4 g = reinterpret_cast<const float4*>(gt_bboxes)[row];
    const float gw = g.z - g.x, gh = g.w - g.y;
    const float gat = atanf(gw / gh);
    const int gl = gt_labels[row];
    const float* sc = pd_scores + (size_t)b * NAA * NCC + gl;
    const float4* pb = reinterpret_cast<const float4*>(pd_bboxes) + (size_t)b * NAA;
    const float2* ap2 = reinterpret_cast<const float2*>(anc);

    __shared__ int   list[LCAP];
    __shared__ int   nlist;
    __shared__ float wv4[4];
    __shared__ int   wi4[4];
    __shared__ int   win[TOPKK];
    __shared__ float Lv[256 * PSTR];
    __shared__ int   Li[256 * PSTR];

    if (tid == 0) nlist = 0;
    __syncthreads();

    // ---- pass 1: compact candidate set ----
    for (int a = tid; a < NAA; a += 256) {
        float2 ap = ap2[a];
        float din = fminf(fminf(ap.x - g.x, ap.y - g.y), fminf(g.z - ap.x, g.w - ap.y));
        bool take = (din > EPSF) || (a < TOPKK);
        unsigned long long m = __ballot(take);
        if (m) {
            int base = 0;
            int wcnt = __popcll(m);
            if (lane == 0) base = atomicAdd(&nlist, wcnt);
            base = __shfl(base, 0, 64);
            if (take) {
                int pos = base + __popcll(m & ((1ull << lane) - 1ull));
                if (pos < LCAP) list[pos] = a;
            }
        }
    }
    __syncthreads();
    int nc = nlist; if (nc > LCAP) nc = LCAP;

    // ---- pass 2: align_metric on candidates, per-thread sorted list ----
    float lv[PDEPTH]; int li[PDEPTH];
#pragma unroll
    for (int k = 0; k < PDEPTH; k++) { lv[k] = -1.f; li[k] = 0x7fffffff; }

    for (int t = tid; t < nc; t += 256) {
        int a = list[t];
        float al = 0.f;
        float2 ap = ap2[a];
        float din = fminf(fminf(ap.x - g.x, ap.y - g.y), fminf(g.z - ap.x, g.w - ap.y));
        if (din > EPSF) {
            float4 p = pb[a];
            float pat = atanf((p.z - p.x) / (p.w - p.y));
            float c = ciou2(g.x, g.y, g.z, g.w, gw, gh, gat, p.x, p.y, p.z, p.w, pat);
            float o = fmaxf(c, 0.f);
            float o2 = o * o;
            al = sc[(size_t)a * NCC] * (o2 * o2 * o2);
        }
        if (al > lv[PDEPTH - 1] || (al == lv[PDEPTH - 1] && a < li[PDEPTH - 1])) {
            lv[PDEPTH - 1] = al; li[PDEPTH - 1] = a;
#pragma unroll
            for (int k = PDEPTH - 1; k > 0; --k) {
                if (lv[k] > lv[k - 1] || (lv[k] == lv[k - 1] && li[k] < li[k - 1])) {
                    float tv = lv[k]; lv[k] = lv[k - 1]; lv[k - 1] = tv;
                    int ti = li[k]; li[k] = li[k - 1]; li[k - 1] = ti;
                } else break;
            }
        }
    }
#pragma unroll
    for (int k = 0; k < PDEPTH; k++) { Lv[tid * PSTR + k] = lv[k]; Li[tid * PSTR + k] = li[k]; }
    Lv[tid * PSTR + PDEPTH] = -1.f;            // sentinel for exhausted head
    Li[tid * PSTR + PDEPTH] = 0x7fffffff;

    // ---- 13-round tournament merge (exact lexicographic order) ----
    int p = 0;
    for (int r = 0; r < TOPKK; ++r) {
        float hv = Lv[tid * PSTR + p];
        int   hi = Li[tid * PSTR + p];
        float wv = hv; int wi = hi;
#pragma unroll
        for (int s = 1; s < 64; s <<= 1) {
            float ov = __shfl_xor(wv, s, 64);
            int   oi = __shfl_xor(wi, s, 64);
            if (ov > wv || (ov == wv && oi < wi)) { wv = ov; wi = oi; }
        }
        if (lane == 0) { wv4[wid] = wv; wi4[wid] = wi; }
        __syncthreads();
        float gv = wv4[0]; int gi = wi4[0];
#pragma unroll
        for (int w = 1; w < 4; ++w) {
            float ov = wv4[w]; int oi = wi4[w];
            if (ov > gv || (ov == gv && oi < gi)) { gv = ov; gi = oi; }
        }
        if (hi == gi) ++p;                      // my head consumed
        if (tid == 0) win[r] = gi;
        __syncthreads();
    }

    // ---- scatter: winners passing mask_in_gts; packed count + (j<<8) ----
    if (tid < TOPKK) {
        int a = win[tid];
        float2 ap = ap2[a];
        float din = fminf(fminf(ap.x - g.x, ap.y - g.y), fminf(g.z - ap.x, g.w - ap.y));
        if (din > EPSF) {
            atomicAdd(&cnt[(size_t)b * NAA + a], 1 + (j << 8));
        }
    }
}

// K2: per-anchor multi-gt resolution + per-row pos_align/pos_ovl maxima.
__global__ __launch_bounds__(256) void k2_resolve(
    const float* __restrict__ pd_scores,
    const float* __restrict__ pd_bboxes,
    const float* __restrict__ anc,
    const int*   __restrict__ gt_labels,
    const float* __restrict__ gt_bboxes,
    const float* __restrict__ mask_gt,
    const int* __restrict__ cnt,
    int* __restrict__ tgt, int* __restrict__ fgm, float* __restrict__ alv,
    unsigned int* __restrict__ pos_al, unsigned int* __restrict__ pos_ov)
{
    const int id = blockIdx.x * 256 + threadIdx.x;   // grid covers exactly B*NA
    const int b = id / NAA;
    const int a = id - b * NAA;
    const int v = cnt[id];
    const int fg = v & 0xff;
    int tj = 0, f = 0;
    float al = 0.f;
    if (fg > 0) {
        f = 1;
        float2 ap = reinterpret_cast<const float2*>(anc)[a];
        float4 p = reinterpret_cast<const float4*>(pd_bboxes)[id];
        float pat = atanf((p.z - p.x) / (p.w - p.y));
        if (fg == 1) {
            tj = v >> 8;
        } else {
            float bv = -1.f; int bj = 0;
            for (int jj = 0; jj < NMX; ++jj) {
                float4 g = reinterpret_cast<const float4*>(gt_bboxes)[b * NMX + jj];
                float din = fminf(fminf(ap.x - g.x, ap.y - g.y), fminf(g.z - ap.x, g.w - ap.y));
                float ov = 0.f;
                if (din > EPSF && mask_gt[b * NMX + jj] > 0.f) {
                    float gw = g.z - g.x, gh = g.w - g.y;
                    float c = ciou2(g.x, g.y, g.z, g.w, gw, gh, atanf(gw / gh),
                                    p.x, p.y, p.z, p.w, pat);
                    ov = fmaxf(c, 0.f);
                }
                if (ov > bv) { bv = ov; bj = jj; }   // strict > == first-argmax
            }
            tj = bj;
        }
        float4 g = reinterpret_cast<const float4*>(gt_bboxes)[b * NMX + tj];
        float din = fminf(fminf(ap.x - g.x, ap.y - g.y), fminf(g.z - ap.x, g.w - ap.y));
        if (din > EPSF && mask_gt[b * NMX + tj] > 0.f) {
            float gw = g.z - g.x, gh = g.w - g.y;
            float c = ciou2(g.x, g.y, g.z, g.w, gw, gh, atanf(gw / gh),
                            p.x, p.y, p.z, p.w, pat);
            float ov = fmaxf(c, 0.f);
            int gl = gt_labels[b * NMX + tj];
            float s = pd_scores[(size_t)id * NCC + gl];
            float o2 = ov * ov;
            al = s * (o2 * o2 * o2);
            atomicMax(&pos_ov[b * NMX + tj], __float_as_uint(ov));
        }
        atomicMax(&pos_al[b * NMX + tj], __float_as_uint(al));
    }
    tgt[id] = tj; fgm[id] = f; alv[id] = al;
}

// K3: all outputs, fully written (no memset pass). Score region written with
// coalesced float4 stores via LDS-staged (label, val) per anchor.
__global__ __launch_bounds__(256) void k3_out(
    const int* __restrict__ gt_labels,
    const float* __restrict__ gt_bboxes,
    const int* __restrict__ tgt, const int* __restrict__ fgm,
    const float* __restrict__ alv,
    const unsigned int* __restrict__ pos_al, const unsigned int* __restrict__ pos_ov,
    float* __restrict__ o_lab, float* __restrict__ o_box, float* __restrict__ o_sc,
    float* __restrict__ o_fg, float* __restrict__ o_ti)
{
    const int id0 = blockIdx.x * 256;
    const int tid = threadIdx.x;
    const int id = id0 + tid;
    const int b = id / NAA;
    const int tj = tgt[id];
    const int f = fgm[id];
    int lab = gt_labels[b * NMX + tj]; lab = lab < 0 ? 0 : lab;
    float4 gb = reinterpret_cast<const float4*>(gt_bboxes)[b * NMX + tj];
    o_lab[id] = (float)lab;
    reinterpret_cast<float4*>(o_box)[id] = gb;
    o_fg[id] = f ? 1.f : 0.f;
    o_ti[id] = (float)tj;
    float val = 0.f;
    if (f) {
        float pa = __uint_as_float(pos_al[b * NMX + tj]);
        float po = __uint_as_float(pos_ov[b * NMX + tj]);
        val = (alv[id] * po) / (pa + EPSF);
    }
    __shared__ int   s_lab[256];
    __shared__ float s_val[256];
    s_lab[tid] = lab;
    s_val[tid] = val;
    __syncthreads();
    float4* dst = reinterpret_cast<float4*>(o_sc + (size_t)id0 * NCC);
    const int NV = 256 * NCC / 4;   // 5120 float4s per block
#pragma unroll 4
    for (int i = tid; i < NV; i += 256) {
        int a  = i / (NCC / 4);
        int c0 = (i - a * (NCC / 4)) * 4;
        int la = s_lab[a];
        float v = s_val[a];
        float4 w;
        w.x = (la == c0 + 0) ? v : 0.f;
        w.y = (la == c0 + 1) ? v : 0.f;
        w.z = (la == c0 + 2) ? v : 0.f;
        w.w = (la == c0 + 3) ? v : 0.f;
        dst[i] = w;
    }
}

extern "C" void kernel_launch(void* const* d_in, const int* in_sizes, int n_in,
                              void* d_out, int out_size, void* d_ws, size_t ws_size,
                              hipStream_t stream)
{
    const float* pd_scores = (const float*)d_in[0];
    const float* pd_bboxes = (const float*)d_in[1];
    const float* anc       = (const float*)d_in[2];
    // d_in[3] rfields: unused by the reference
    const int*   gt_labels = (const int*)d_in[4];
    const float* gt_bboxes = (const float*)d_in[5];
    const float* mask_gt   = (const float*)d_in[6];

    const size_t nba  = (size_t)BB * NAA;   // 134400
    const size_t nrow = (size_t)BB * NMX;   // 1024
    // contiguous zero region first: cnt | pos_al | pos_ov
    int* cnt   = (int*)d_ws;
    unsigned int* pos_al = (unsigned int*)(cnt + nba);
    unsigned int* pos_ov = pos_al + nrow;
    int* tgt   = (int*)(pos_ov + nrow);
    int* fgm   = tgt + nba;
    float* alv = (float*)(fgm + nba);

    float* out = (float*)d_out;
    float* o_lab = out;                 // (B,NA)
    float* o_box = out + nba;           // (B,NA,4)
    float* o_sc  = out + nba * 5;       // (B,NA,NC)
    float* o_fg  = out + nba * 85;      // (B,NA)
    float* o_ti  = out + nba * 86;      // (B,NA)

    kz_zero<<<(NZI4 + 255) / 256, 256, 0, stream>>>((int4*)d_ws);
    k1_topk<<<(int)nrow, 256, 0, stream>>>(pd_scores, pd_bboxes, anc, gt_labels,
                                           gt_bboxes, mask_gt, cnt);
    const int nblk = (int)(nba / 256);   // 525, exact
    k2_resolve<<<nblk, 256, 0, stream>>>(pd_scores, pd_bboxes, anc, gt_labels,
                                         gt_bboxes, mask_gt, cnt,
                                         tgt, fgm, alv, pos_al, pos_ov);
    k3_out<<<nblk, 256, 0, stream>>>(gt_labels, gt_bboxes, tgt, fgm, alv,
                                     pos_al, pos_ov, o_lab, o_box, o_sc, o_fg, o_ti);
}